// Round 3
// baseline (11.308 us; speedup 1.0000x reference)
//
#include <hip/hip_runtime.h>
#include <hip/hip_bf16.h>

#define NFEAT    16
#define NMF      7
#define NCLASSES 10
#define NRULES   512
#define BATCH    16384

#define WAVES 8
#define BLOCK (WAVES * 64)   // 512 threads; 64 samples/block; lane=sample (stages 1/rare), lane=rule (stage 2)

static_assert(BATCH % 64 == 0, "");
static_assert(NRULES == BLOCK, "one rule per thread in stage 2");

__global__ __launch_bounds__(BLOCK) void nefclass_kernel(
    const float* __restrict__ x,        // (NFEAT, BATCH)
    const float* __restrict__ mf_abc,   // (NFEAT, NMF, 3)
    const int*   __restrict__ rcond,    // (NRULES, NFEAT)
    const int*   __restrict__ rcls,     // (NRULES,)
    float*       __restrict__ out)      // (BATCH, NCLASSES)
{
    __shared__ unsigned long long lmask[NFEAT * NMF]; //   896 B, bit j = (mem > 0) for sample j
    __shared__ float mem[NFEAT * NMF][64];            // 28672 B (rare path only)
    __shared__ float acc[WAVES][NCLASSES][64];        // 20480 B (rare path only)

    const int tid   = threadIdx.x;
    const int lane  = tid & 63;
    const int wave  = tid >> 6;
    const int sbase = blockIdx.x * 64;

    // ---- hoisted: per-rule conditions (independent of stage 1 -> overlap latency) ----
    const int r0 = wave * 64;
    const int r  = r0 + lane;
    const int4* rc = (const int4*)(rcond + r * NFEAT);  // 64 B per rule
    const int4 c0 = rc[0], c1 = rc[1], c2 = rc[2], c3 = rc[3];

    // ---- stage 1 (fast): sign masks only, no divides. wave w owns features 2w, 2w+1 ----
    const int   f0  = wave * 2;
    const float xv0 = x[(f0 + 0) * BATCH + sbase + lane];
    const float xv1 = x[(f0 + 1) * BATCH + sbase + lane];
    #pragma unroll
    for (int ff = 0; ff < 2; ++ff) {
        const float xv = ff ? xv1 : xv0;
        const int   f  = f0 + ff;
        #pragma unroll
        for (int m = 0; m < NMF; ++m) {
            const int p = f * NMF + m;
            const float a = mf_abc[p * 3 + 0];
            const float c = mf_abc[p * 3 + 2];
            // v > 0  <=>  xv > a && xv < c   (divisors b-a, c-b are positive)
            const unsigned long long bm = __ballot(xv > a && xv < c);
            if (lane == 0) lmask[p] = bm;
        }
    }
    __syncthreads();

    // ---- stage 2: lane = rule. AND 16 selected masks -> per-rule sample mask ----
    unsigned long long rm = lmask[ 0 * NMF + c0.x];
    rm &= lmask[ 1 * NMF + c0.y];
    rm &= lmask[ 2 * NMF + c0.z];
    rm &= lmask[ 3 * NMF + c0.w];
    rm &= lmask[ 4 * NMF + c1.x];
    rm &= lmask[ 5 * NMF + c1.y];
    rm &= lmask[ 6 * NMF + c1.z];
    rm &= lmask[ 7 * NMF + c1.w];
    rm &= lmask[ 8 * NMF + c2.x];
    rm &= lmask[ 9 * NMF + c2.y];
    rm &= lmask[10 * NMF + c2.z];
    rm &= lmask[11 * NMF + c2.w];
    rm &= lmask[12 * NMF + c3.x];
    rm &= lmask[13 * NMF + c3.y];
    rm &= lmask[14 * NMF + c3.z];
    rm &= lmask[15 * NMF + c3.w];

    unsigned long long fired = __ballot(rm != 0ull);        // wave-uniform
    const int any = __syncthreads_or(fired != 0ull ? 1 : 0);

    if (!any) {
        // every firing in this block is exactly 0 -> output is exactly zero
        if (tid < 64 * NCLASSES / 4)   // 160 float4 stores
            ((float4*)(out + sbase * NCLASSES))[tid] = make_float4(0.f, 0.f, 0.f, 0.f);
        return;
    }

    // ---- rare path: full memberships (reference-exact divides), then fired rules only ----
    #pragma unroll
    for (int ff = 0; ff < 2; ++ff) {
        const float xv = ff ? xv1 : xv0;
        const int   f  = f0 + ff;
        #pragma unroll
        for (int m = 0; m < NMF; ++m) {
            const int p = f * NMF + m;
            const float a = mf_abc[p * 3 + 0];
            const float b = mf_abc[p * 3 + 1];
            const float c = mf_abc[p * 3 + 2];
            float v = fminf((xv - a) / (b - a), (c - xv) / (c - b));
            mem[p][lane] = fminf(fmaxf(v, 0.0f), 1.0f);
        }
    }
    #pragma unroll
    for (int c = 0; c < NCLASSES; ++c) acc[wave][c][lane] = 0.0f;
    __syncthreads();

    while (fired != 0ull) {                    // ascending rule index within wave
        const int b = __ffsll(fired) - 1;
        fired &= fired - 1;
        const int rr = r0 + b;
        float fir = 1.0f;                      // memberships <= 1 -> identity for min
        #pragma unroll
        for (int f = 0; f < NFEAT; ++f) {
            const int m = rcond[rr * NFEAT + f];          // wave-uniform
            fir = fminf(fir, mem[f * NMF + m][lane]);     // broadcast row, lane=sample
        }
        const int c = rcls[rr];                // wave-uniform
        acc[wave][c][lane] += fir;
    }
    __syncthreads();

    // waves hold disjoint, ascending rule ranges -> matches reference segment_sum order
    for (int o = tid; o < 64 * NCLASSES; o += BLOCK) {
        const int s = o / NCLASSES;
        const int c = o - s * NCLASSES;
        float vsum = 0.0f;
        #pragma unroll
        for (int w = 0; w < WAVES; ++w) vsum += acc[w][c][s];
        out[sbase * NCLASSES + o] = vsum;
    }
}

extern "C" void kernel_launch(void* const* d_in, const int* in_sizes, int n_in,
                              void* d_out, int out_size, void* d_ws, size_t ws_size,
                              hipStream_t stream)
{
    const float* x     = (const float*)d_in[0];
    const float* mf    = (const float*)d_in[1];
    const int*   rcond = (const int*)d_in[2];
    const int*   rcls  = (const int*)d_in[3];
    float*       out   = (float*)d_out;

    nefclass_kernel<<<dim3(BATCH / 64), dim3(BLOCK), 0, stream>>>(x, mf, rcond, rcls, out);
}